// Round 7
// baseline (177.177 us; speedup 1.0000x reference)
//
#include <hip/hip_runtime.h>
#include <hip/hip_bf16.h>

// B=4, S=4096, E=512, D=64. Causal single-head attention, scale = 1/sqrt(E).
namespace {
constexpr int B = 4, S = 4096, E = 512, D = 64;
constexpr int CHUNK = 8;                      // K-tiles per attention block
// p = exp(scale*s) = exp2(C*s), C = (1/sqrt(512))*log2(e)
constexpr float SCALE_LOG2E = 0.04419417382415922f * 1.4426950408889634f;

typedef __bf16 bf16x8 __attribute__((ext_vector_type(8)));
typedef float floatx4 __attribute__((ext_vector_type(4)));
} // namespace

// ---------------------------------------------------------------------------
// Kernel 0: weight transpose + bf16 cast via LDS tile. Wt[mat][n][k]=W[k][n].
// ---------------------------------------------------------------------------
__global__ __launch_bounds__(256) void prep_wt(
    const float* __restrict__ WQ, const float* __restrict__ WK,
    const float* __restrict__ WV, __bf16* __restrict__ Wt)
{
    __shared__ __bf16 tile[64][72];
    const int t = threadIdx.x;
    const int mat = blockIdx.x >> 3;          // 0..2
    const int k0  = (blockIdx.x & 7) * 64;    // k tile base
    const float* W = (mat == 0) ? WQ : (mat == 1) ? WK : WV;
    #pragma unroll
    for (int i = 0; i < 16; ++i) {
        const int k = (t >> 6) + i * 4;       // lanes vary n -> coalesced read
        tile[t & 63][k] = (__bf16)W[(k0 + k) * 64 + (t & 63)];
    }
    __syncthreads();
    #pragma unroll
    for (int i = 0; i < 2; ++i) {
        const int u = t + 256 * i;            // 512 units: 64 n x 8 k-segs
        const int n = u >> 3, kseg = (u & 7) * 8;
        *(bf16x8*)(Wt + (mat * 64 + n) * 512 + k0 + kseg) =
            *(const bf16x8*)&tile[n][kseg];
    }
}

// ---------------------------------------------------------------------------
// Kernel 1: fused QKV projection as MFMA GEMM [16384 x 512] x [512 x 192].
// B-fragments (Wt) loaded directly from global (L2-resident); x tile staged
// through LDS with register prefetch pipeline. (unchanged from round 6)
// ---------------------------------------------------------------------------
__global__ __launch_bounds__(256) void qkv_mfma(
    const float* __restrict__ x, const __bf16* __restrict__ Wt,
    __bf16* __restrict__ Qb, __bf16* __restrict__ Kb, __bf16* __restrict__ Vt)
{
    __shared__ __bf16 xs[32][72];    // [row][k] staged x tile
    __shared__ __bf16 vsh[64][40];   // V transpose buffer [d][m]

    const int t = threadIdx.x;
    const int wave = t >> 6, lane = t & 63, quad = lane >> 4, l16 = lane & 15;
    const long row0 = (long)blockIdx.x * 32;
    const int xrr = t >> 3, xcc = (t & 7) * 8;   // x staging coords

    const __bf16* wbase = Wt + (wave * 48 + l16) * 512 + quad * 8;

    floatx4 acc[2][3];
    #pragma unroll
    for (int m = 0; m < 2; ++m)
        #pragma unroll
        for (int n = 0; n < 3; ++n) acc[m][n] = (floatx4){0.f, 0.f, 0.f, 0.f};

    float4 xf0, xf1;
    bf16x8 wf[6];
    {
        const float* src = x + (row0 + xrr) * E + xcc;
        xf0 = *(const float4*)src;
        xf1 = *(const float4*)(src + 4);
        #pragma unroll
        for (int ns = 0; ns < 3; ++ns)
            #pragma unroll
            for (int ch = 0; ch < 2; ++ch)
                wf[ns * 2 + ch] = *(const bf16x8*)(wbase + ns * 16 * 512 + ch * 32);
    }

    #pragma unroll
    for (int kc = 0; kc < 8; ++kc) {
        __syncthreads();
        {   // commit prefetched x regs to LDS (fp32 -> bf16)
            bf16x8 v;
            v[0] = (__bf16)xf0.x; v[1] = (__bf16)xf0.y;
            v[2] = (__bf16)xf0.z; v[3] = (__bf16)xf0.w;
            v[4] = (__bf16)xf1.x; v[5] = (__bf16)xf1.y;
            v[6] = (__bf16)xf1.z; v[7] = (__bf16)xf1.w;
            *(bf16x8*)&xs[xrr][xcc] = v;
        }
        __syncthreads();

        bf16x8 wcur[6];
        #pragma unroll
        for (int i = 0; i < 6; ++i) wcur[i] = wf[i];

        if (kc < 7) {
            const float* src = x + (row0 + xrr) * E + (kc + 1) * 64 + xcc;
            xf0 = *(const float4*)src;
            xf1 = *(const float4*)(src + 4);
            #pragma unroll
            for (int ns = 0; ns < 3; ++ns)
                #pragma unroll
                for (int ch = 0; ch < 2; ++ch)
                    wf[ns * 2 + ch] =
                        *(const bf16x8*)(wbase + ns * 16 * 512 + (kc + 1) * 64 + ch * 32);
        }

        bf16x8 aa[2][2];
        #pragma unroll
        for (int m = 0; m < 2; ++m)
            #pragma unroll
            for (int ch = 0; ch < 2; ++ch)
                aa[m][ch] = *(const bf16x8*)&xs[m * 16 + l16][ch * 32 + quad * 8];
        #pragma unroll
        for (int ns = 0; ns < 3; ++ns) {
            #pragma unroll
            for (int ch = 0; ch < 2; ++ch) {
                #pragma unroll
                for (int m = 0; m < 2; ++m)
                    acc[m][ns] = __builtin_amdgcn_mfma_f32_16x16x32_bf16(
                        aa[m][ch], wcur[ns * 2 + ch], acc[m][ns], 0, 0, 0);
            }
        }
    }

    const long bb_ = row0 >> 12;
    const int s0 = (int)(row0 & 4095);
    #pragma unroll
    for (int ns = 0; ns < 3; ++ns) {
        const int g = wave * 3 + ns;
        const int mat = g >> 2;
        const int col = (g & 3) * 16 + l16;
        #pragma unroll
        for (int m = 0; m < 2; ++m) {
            if (mat < 2) {
                __bf16* Out = (mat == 0) ? Qb : Kb;
                #pragma unroll
                for (int r = 0; r < 4; ++r)
                    Out[(row0 + m * 16 + quad * 4 + r) * 64 + col] = (__bf16)acc[m][ns][r];
            } else {
                __bf16 p[4];
                #pragma unroll
                for (int r = 0; r < 4; ++r) p[r] = (__bf16)acc[m][ns][r];
                *(unsigned long long*)&vsh[col][m * 16 + quad * 4] = *(unsigned long long*)p;
            }
        }
    }
    __syncthreads();
    {
        const int d = t >> 2, seg = (t & 3) * 8;
        bf16x8 v = *(const bf16x8*)&vsh[d][seg];
        *(bf16x8*)(Vt + (bb_ * 64 + d) * 4096 + s0 + seg) = v;
    }
}

// ---------------------------------------------------------------------------
// Kernel 2 v3: BARRIER-FREE causal flash attention, balanced K-split.
// Operand-swapped MFMAs (A/B lane maps are identical, HW-verified m89):
//   St = K.Q^T   -> lane holds St[key=quad*4+r][q=l16]  (C-layout)
//   P^T write: lane packs its 4 keys for row q=l16 -> one b64 per subtile
//   lsum = mfma(ones, ap): D[m][n] = sum_key P[q=n][key], all regs equal
//   Ot = V.P^T   -> lane holds Ot[d=quad*4+r][q=l16]; epilogue = 4x8B stores
// K and V^T A-fragments are 16 contiguous bytes per lane -> loaded DIRECTLY
// from global (L2-resident, ~530 MB total) — no K/V LDS staging, and since
// Ps is per-wave, NO __syncthreads() anywhere in the loop.
// ---------------------------------------------------------------------------
__global__ __launch_bounds__(256) void attn_kernel(
    const __bf16* __restrict__ Qg, const __bf16* __restrict__ Kg,
    const __bf16* __restrict__ Vt, __bf16* __restrict__ Opart,
    float* __restrict__ Lpart)
{
    __shared__ __bf16 Ps[4][16][72];  // per-wave P [q][key]

    // decode blockIdx.x -> (qt, chunk): group a = qt>>3 starts at 4a(a+1)
    int g = blockIdx.x;               // 0..287
    int a = 0;
    while (g >= 4 * (a + 1) * (a + 2)) ++a;
    const int rem = g - 4 * a * (a + 1);
    const int qt  = 8 * a + rem / (a + 1);
    const int c   = rem % (a + 1);

    const int b  = blockIdx.y;
    const int q0 = qt * 64;
    const int t  = threadIdx.x;
    const int wave = t >> 6, lane = t & 63, quad = lane >> 4, l16 = lane & 15;

    const int nkt    = qt + 1;
    const int kstart = c * CHUNK;
    const int kend   = min(kstart + CHUNK, nkt);

    // Q fragments (serve as MFMA B operands for St)
    const __bf16* qrow = Qg + ((long)(b * S + q0 + wave * 16 + l16)) * D;
    bf16x8 aq[2];
    aq[0] = *(const bf16x8*)(qrow + quad * 8);
    aq[1] = *(const bf16x8*)(qrow + 32 + quad * 8);

    bf16x8 ones;
    #pragma unroll
    for (int j = 0; j < 8; ++j) ones[j] = (__bf16)1.0f;

    floatx4 o[4];                     // Ot layout: [d-subtile][regs over d]
    #pragma unroll
    for (int i = 0; i < 4; ++i) o[i] = (floatx4){0.f, 0.f, 0.f, 0.f};
    floatx4 lsum = (floatx4){0.f, 0.f, 0.f, 0.f};

    const __bf16* Kb_ = Kg + (long)b * S * D;       // + key*64 + d
    const __bf16* Vb_ = Vt + (long)b * 64 * 4096;   // + d*4096 + key

    for (int ktg = kstart; ktg < kend; ++ktg) {
        const int kbase = ktg * 64;

        // K A-fragments direct from global: row = key (ns*16+l16), k-dim = d
        bf16x8 kfr[4][2];
        #pragma unroll
        for (int ns = 0; ns < 4; ++ns)
            #pragma unroll
            for (int ch = 0; ch < 2; ++ch)
                kfr[ns][ch] = *(const bf16x8*)(
                    Kb_ + (long)(kbase + ns * 16 + l16) * 64 + ch * 32 + quad * 8);

        // V A-fragments direct from global: row = d (dsb*16+l16), k-dim = key
        bf16x8 vfr[4][2];
        #pragma unroll
        for (int dsb = 0; dsb < 4; ++dsb)
            #pragma unroll
            for (int ch = 0; ch < 2; ++ch)
                vfr[dsb][ch] = *(const bf16x8*)(
                    Vb_ + (long)(dsb * 16 + l16) * 4096 + kbase + ch * 32 + quad * 8);

        // St = K.Q^T (4 key sub-tiles of 16)
        floatx4 sf[4];
        #pragma unroll
        for (int ns = 0; ns < 4; ++ns) {
            floatx4 cacc = (floatx4){0.f, 0.f, 0.f, 0.f};
            #pragma unroll
            for (int ch = 0; ch < 2; ++ch)
                cacc = __builtin_amdgcn_mfma_f32_16x16x32_bf16(
                    kfr[ns][ch], aq[ch], cacc, 0, 0, 0);
            sf[ns] = cacc;
        }

        if (ktg == nkt - 1) {   // diagonal tile: causal mask (St indexing!)
            const int q = q0 + wave * 16 + l16;
            #pragma unroll
            for (int ns = 0; ns < 4; ++ns)
                #pragma unroll
                for (int r = 0; r < 4; ++r) {
                    const int key = kbase + ns * 16 + quad * 4 + r;
                    if (key > q) sf[ns][r] = -1e30f;
                }
        }

        // p = exp2(s*C); lane packs 4 keys of row q=l16 -> one b64 per ns
        #pragma unroll
        for (int ns = 0; ns < 4; ++ns) {
            __bf16 p4[4];
            #pragma unroll
            for (int r = 0; r < 4; ++r)
                p4[r] = (__bf16)__builtin_amdgcn_exp2f(sf[ns][r] * SCALE_LOG2E);
            *(unsigned long long*)&Ps[wave][l16][ns * 16 + quad * 4] =
                *(unsigned long long*)p4;
        }

        // P fragments (B operands): row q=l16, keys ch*32+quad*8..+7
        bf16x8 ap[2];
        ap[0] = *(const bf16x8*)&Ps[wave][l16][quad * 8];
        ap[1] = *(const bf16x8*)&Ps[wave][l16][32 + quad * 8];

        // l[q] += sum_key P[q][key]  (every reg/row identical)
        lsum = __builtin_amdgcn_mfma_f32_16x16x32_bf16(ones, ap[0], lsum, 0, 0, 0);
        lsum = __builtin_amdgcn_mfma_f32_16x16x32_bf16(ones, ap[1], lsum, 0, 0, 0);

        // Ot += V.P^T
        #pragma unroll
        for (int dsb = 0; dsb < 4; ++dsb) {
            floatx4 cacc = o[dsb];
            #pragma unroll
            for (int ch = 0; ch < 2; ++ch)
                cacc = __builtin_amdgcn_mfma_f32_16x16x32_bf16(
                    vfr[dsb][ch], ap[ch], cacc, 0, 0, 0);
            o[dsb] = cacc;
        }
    }

    // Epilogue: lane owns q = l16, d = dsb*16 + quad*4 + 0..3 -> 4 x 8B stores
    const long rbase = (long)c * (B * S) + (long)b * S + q0 + wave * 16;
    #pragma unroll
    for (int dsb = 0; dsb < 4; ++dsb) {
        __bf16 p4[4];
        #pragma unroll
        for (int r = 0; r < 4; ++r) p4[r] = (__bf16)o[dsb][r];
        *(unsigned long long*)(Opart + (rbase + l16) * 64 + dsb * 16 + quad * 4) =
            *(unsigned long long*)p4;
    }
    if (quad == 0)
        Lpart[rbase + l16] = lsum[0];
}

// ---------------------------------------------------------------------------
// Kernel 3: combine K-split partials: O = (sum_c O_c) / (sum_c l_c),
// summing only the nc(qt) chunks that exist for this row's q-tile.
// ---------------------------------------------------------------------------
__global__ __launch_bounds__(256) void combine_kernel(
    const __bf16* __restrict__ Opart, const float* __restrict__ Lpart,
    float* __restrict__ Og)
{
    const int idx = blockIdx.x * 256 + threadIdx.x;   // over B*S*8
    const int row = idx >> 3, seg = (idx & 7) * 8;
    const int qt = (row & (S - 1)) >> 6;
    const int nc = (qt >> 3) + 1;                     // ceil((qt+1)/8)
    float acc[8] = {0, 0, 0, 0, 0, 0, 0, 0};
    float l = 0.f;
    for (int c = 0; c < nc; ++c) {
        bf16x8 ov = *(const bf16x8*)(Opart + ((long)c * (B * S) + row) * 64 + seg);
        l += Lpart[(long)c * (B * S) + row];
        #pragma unroll
        for (int j = 0; j < 8; ++j) acc[j] += (float)ov[j];
    }
    const float invl = 1.f / l;
    float* dst = Og + (long)row * 64 + seg;
    float4 o0 = {acc[0] * invl, acc[1] * invl, acc[2] * invl, acc[3] * invl};
    float4 o1 = {acc[4] * invl, acc[5] * invl, acc[6] * invl, acc[7] * invl};
    *(float4*)dst = o0;
    *(float4*)(dst + 4) = o1;
}

extern "C" void kernel_launch(void* const* d_in, const int* in_sizes, int n_in,
                              void* d_out, int out_size, void* d_ws, size_t ws_size,
                              hipStream_t stream)
{
    const float* x  = (const float*)d_in[0];
    const float* WQ = (const float*)d_in[1];
    const float* WK = (const float*)d_in[2];
    const float* WV = (const float*)d_in[3];
    float* out = (float*)d_out;

    __bf16* Qb = (__bf16*)d_ws;                       // [B*S, 64]        2 MB
    __bf16* Kb = Qb + (size_t)B * S * D;              //                  2 MB
    __bf16* Vt = Kb + (size_t)B * S * D;              // [B, 64, S]       2 MB
    __bf16* Wt = Vt + (size_t)B * S * D;              // [3, 64, 512]   192 KB
    __bf16* Opart = Wt + (size_t)3 * E * D;           // [8, B*S, 64]    16 MB
    float*  Lpart = (float*)(Opart + (size_t)8 * B * S * D);  // [8,B*S] 512 KB

    prep_wt<<<dim3(24), 256, 0, stream>>>(WQ, WK, WV, Wt);
    qkv_mfma<<<dim3((B * S) / 32), 256, 0, stream>>>(x, Wt, Qb, Kb, Vt);
    attn_kernel<<<dim3(288, B), 256, 0, stream>>>(Qb, Kb, Vt, Opart, Lpart);
    combine_kernel<<<dim3((B * S * 8) / 256), 256, 0, stream>>>(Opart, Lpart, out);
}

// Round 8
// 170.079 us; speedup vs baseline: 1.0417x; 1.0417x over previous
//
#include <hip/hip_runtime.h>
#include <hip/hip_bf16.h>

// B=4, S=4096, E=512, D=64. Causal single-head attention, scale = 1/sqrt(E).
namespace {
constexpr int B = 4, S = 4096, E = 512, D = 64;
constexpr int CHUNK = 8;                      // K-tiles per attention block
// p = exp(scale*s) = exp2(C*s), C = (1/sqrt(512))*log2(e)
constexpr float SCALE_LOG2E = 0.04419417382415922f * 1.4426950408889634f;

typedef __bf16 bf16x8 __attribute__((ext_vector_type(8)));
typedef float floatx4 __attribute__((ext_vector_type(4)));
} // namespace

// ---------------------------------------------------------------------------
// Kernel 0: weight transpose + bf16 cast via LDS tile. Wt[mat][n][k]=W[k][n].
// ---------------------------------------------------------------------------
__global__ __launch_bounds__(256) void prep_wt(
    const float* __restrict__ WQ, const float* __restrict__ WK,
    const float* __restrict__ WV, __bf16* __restrict__ Wt)
{
    __shared__ __bf16 tile[64][72];
    const int t = threadIdx.x;
    const int mat = blockIdx.x >> 3;          // 0..2
    const int k0  = (blockIdx.x & 7) * 64;    // k tile base
    const float* W = (mat == 0) ? WQ : (mat == 1) ? WK : WV;
    #pragma unroll
    for (int i = 0; i < 16; ++i) {
        const int k = (t >> 6) + i * 4;       // lanes vary n -> coalesced read
        tile[t & 63][k] = (__bf16)W[(k0 + k) * 64 + (t & 63)];
    }
    __syncthreads();
    #pragma unroll
    for (int i = 0; i < 2; ++i) {
        const int u = t + 256 * i;            // 512 units: 64 n x 8 k-segs
        const int n = u >> 3, kseg = (u & 7) * 8;
        *(bf16x8*)(Wt + (mat * 64 + n) * 512 + k0 + kseg) =
            *(const bf16x8*)&tile[n][kseg];
    }
}

// ---------------------------------------------------------------------------
// Kernel 1: fused QKV projection as MFMA GEMM [16384 x 512] x [512 x 192].
// B-fragments (Wt) loaded directly from global (L2-resident); x tile staged
// through LDS with register prefetch pipeline. (unchanged from round 6)
// ---------------------------------------------------------------------------
__global__ __launch_bounds__(256) void qkv_mfma(
    const float* __restrict__ x, const __bf16* __restrict__ Wt,
    __bf16* __restrict__ Qb, __bf16* __restrict__ Kb, __bf16* __restrict__ Vt)
{
    __shared__ __bf16 xs[32][72];    // [row][k] staged x tile
    __shared__ __bf16 vsh[64][40];   // V transpose buffer [d][m]

    const int t = threadIdx.x;
    const int wave = t >> 6, lane = t & 63, quad = lane >> 4, l16 = lane & 15;
    const long row0 = (long)blockIdx.x * 32;
    const int xrr = t >> 3, xcc = (t & 7) * 8;   // x staging coords

    const __bf16* wbase = Wt + (wave * 48 + l16) * 512 + quad * 8;

    floatx4 acc[2][3];
    #pragma unroll
    for (int m = 0; m < 2; ++m)
        #pragma unroll
        for (int n = 0; n < 3; ++n) acc[m][n] = (floatx4){0.f, 0.f, 0.f, 0.f};

    float4 xf0, xf1;
    bf16x8 wf[6];
    {
        const float* src = x + (row0 + xrr) * E + xcc;
        xf0 = *(const float4*)src;
        xf1 = *(const float4*)(src + 4);
        #pragma unroll
        for (int ns = 0; ns < 3; ++ns)
            #pragma unroll
            for (int ch = 0; ch < 2; ++ch)
                wf[ns * 2 + ch] = *(const bf16x8*)(wbase + ns * 16 * 512 + ch * 32);
    }

    #pragma unroll
    for (int kc = 0; kc < 8; ++kc) {
        __syncthreads();
        {   // commit prefetched x regs to LDS (fp32 -> bf16)
            bf16x8 v;
            v[0] = (__bf16)xf0.x; v[1] = (__bf16)xf0.y;
            v[2] = (__bf16)xf0.z; v[3] = (__bf16)xf0.w;
            v[4] = (__bf16)xf1.x; v[5] = (__bf16)xf1.y;
            v[6] = (__bf16)xf1.z; v[7] = (__bf16)xf1.w;
            *(bf16x8*)&xs[xrr][xcc] = v;
        }
        __syncthreads();

        bf16x8 wcur[6];
        #pragma unroll
        for (int i = 0; i < 6; ++i) wcur[i] = wf[i];

        if (kc < 7) {
            const float* src = x + (row0 + xrr) * E + (kc + 1) * 64 + xcc;
            xf0 = *(const float4*)src;
            xf1 = *(const float4*)(src + 4);
            #pragma unroll
            for (int ns = 0; ns < 3; ++ns)
                #pragma unroll
                for (int ch = 0; ch < 2; ++ch)
                    wf[ns * 2 + ch] =
                        *(const bf16x8*)(wbase + ns * 16 * 512 + (kc + 1) * 64 + ch * 32);
        }

        bf16x8 aa[2][2];
        #pragma unroll
        for (int m = 0; m < 2; ++m)
            #pragma unroll
            for (int ch = 0; ch < 2; ++ch)
                aa[m][ch] = *(const bf16x8*)&xs[m * 16 + l16][ch * 32 + quad * 8];
        #pragma unroll
        for (int ns = 0; ns < 3; ++ns) {
            #pragma unroll
            for (int ch = 0; ch < 2; ++ch) {
                #pragma unroll
                for (int m = 0; m < 2; ++m)
                    acc[m][ns] = __builtin_amdgcn_mfma_f32_16x16x32_bf16(
                        aa[m][ch], wcur[ns * 2 + ch], acc[m][ns], 0, 0, 0);
            }
        }
    }

    const long bb_ = row0 >> 12;
    const int s0 = (int)(row0 & 4095);
    #pragma unroll
    for (int ns = 0; ns < 3; ++ns) {
        const int g = wave * 3 + ns;
        const int mat = g >> 2;
        const int col = (g & 3) * 16 + l16;
        #pragma unroll
        for (int m = 0; m < 2; ++m) {
            if (mat < 2) {
                __bf16* Out = (mat == 0) ? Qb : Kb;
                #pragma unroll
                for (int r = 0; r < 4; ++r)
                    Out[(row0 + m * 16 + quad * 4 + r) * 64 + col] = (__bf16)acc[m][ns][r];
            } else {
                __bf16 p[4];
                #pragma unroll
                for (int r = 0; r < 4; ++r) p[r] = (__bf16)acc[m][ns][r];
                *(unsigned long long*)&vsh[col][m * 16 + quad * 4] = *(unsigned long long*)p;
            }
        }
    }
    __syncthreads();
    {
        const int d = t >> 2, seg = (t & 3) * 8;
        bf16x8 v = *(const bf16x8*)&vsh[d][seg];
        *(bf16x8*)(Vt + (bb_ * 64 + d) * 4096 + s0 + seg) = v;
    }
}

// ---------------------------------------------------------------------------
// Kernel 2 v4: barrier-free causal flash attention, balanced K-split,
// SOFTWARE-PIPELINED direct-global fragment loads. V fragments issued at
// tile top (covered by St+softmax); K fragments for tile n+1 refilled
// in-place right after tile n's St MFMAs. Heavy-first block order.
// Operand-swapped MFMAs: St = K.Q^T; P^T packed b64; lsum = mfma(ones,ap);
// Ot = V.P^T.
// ---------------------------------------------------------------------------
__global__ __launch_bounds__(256) void attn_kernel(
    const __bf16* __restrict__ Qg, const __bf16* __restrict__ Kg,
    const __bf16* __restrict__ Vt, __bf16* __restrict__ Opart,
    float* __restrict__ Lpart)
{
    __shared__ __bf16 Ps[4][16][72];  // per-wave P [q][key]

    // decode (heavy-first) blockIdx.x -> (qt, chunk)
    int g = 287 - blockIdx.x;         // large g = large qt = heavy chunk
    int a = 0;
    while (g >= 4 * (a + 1) * (a + 2)) ++a;      // a = qt>>3
    const int rem = g - 4 * a * (a + 1);
    const int qt  = 8 * a + rem / (a + 1);
    const int c   = rem % (a + 1);

    const int b  = blockIdx.y;
    const int q0 = qt * 64;
    const int t  = threadIdx.x;
    const int wave = t >> 6, lane = t & 63, quad = lane >> 4, l16 = lane & 15;

    const int nkt    = qt + 1;
    const int kstart = c * CHUNK;
    const int kend   = min(kstart + CHUNK, nkt);

    // Q fragments (MFMA B operands for St)
    const __bf16* qrow = Qg + ((long)(b * S + q0 + wave * 16 + l16)) * D;
    bf16x8 aq[2];
    aq[0] = *(const bf16x8*)(qrow + quad * 8);
    aq[1] = *(const bf16x8*)(qrow + 32 + quad * 8);

    bf16x8 ones;
    #pragma unroll
    for (int j = 0; j < 8; ++j) ones[j] = (__bf16)1.0f;

    floatx4 o[4];                     // Ot: [d-subtile][regs over d]
    #pragma unroll
    for (int i = 0; i < 4; ++i) o[i] = (floatx4){0.f, 0.f, 0.f, 0.f};
    floatx4 lsum = (floatx4){0.f, 0.f, 0.f, 0.f};

    const __bf16* Kb_ = Kg + (long)b * S * D;       // + key*64 + d
    const __bf16* Vb_ = Vt + (long)b * 64 * 4096;   // + d*4096 + key

    // ---- prologue: K fragments for the first tile (only exposed latency)
    bf16x8 kf[4][2];
    #pragma unroll
    for (int ns = 0; ns < 4; ++ns)
        #pragma unroll
        for (int ch = 0; ch < 2; ++ch)
            kf[ns][ch] = *(const bf16x8*)(
                Kb_ + (long)(kstart * 64 + ns * 16 + l16) * 64 + ch * 32 + quad * 8);

    for (int ktg = kstart; ktg < kend; ++ktg) {
        const int kbase = ktg * 64;

        // V fragments for THIS tile: issue now, consumed after softmax
        bf16x8 vfr[4][2];
        #pragma unroll
        for (int dsb = 0; dsb < 4; ++dsb)
            #pragma unroll
            for (int ch = 0; ch < 2; ++ch)
                vfr[dsb][ch] = *(const bf16x8*)(
                    Vb_ + (long)(dsb * 16 + l16) * 4096 + kbase + ch * 32 + quad * 8);

        // St = K.Q^T (consumes kf)
        floatx4 sf[4];
        #pragma unroll
        for (int ns = 0; ns < 4; ++ns) {
            floatx4 cacc = (floatx4){0.f, 0.f, 0.f, 0.f};
            #pragma unroll
            for (int ch = 0; ch < 2; ++ch)
                cacc = __builtin_amdgcn_mfma_f32_16x16x32_bf16(
                    kf[ns][ch], aq[ch], cacc, 0, 0, 0);
            sf[ns] = cacc;
        }

        // K fragments for NEXT tile: in-place refill (WAR at issue, no stall)
        if (ktg + 1 < kend) {
            #pragma unroll
            for (int ns = 0; ns < 4; ++ns)
                #pragma unroll
                for (int ch = 0; ch < 2; ++ch)
                    kf[ns][ch] = *(const bf16x8*)(
                        Kb_ + (long)(kbase + 64 + ns * 16 + l16) * 64 + ch * 32 + quad * 8);
        }

        if (ktg == nkt - 1) {   // diagonal tile: causal mask (St indexing)
            const int q = q0 + wave * 16 + l16;
            #pragma unroll
            for (int ns = 0; ns < 4; ++ns)
                #pragma unroll
                for (int r = 0; r < 4; ++r) {
                    const int key = kbase + ns * 16 + quad * 4 + r;
                    if (key > q) sf[ns][r] = -1e30f;
                }
        }

        // p = exp2(s*C); lane packs its 4 keys of row q=l16 -> b64 per ns
        #pragma unroll
        for (int ns = 0; ns < 4; ++ns) {
            __bf16 p4[4];
            #pragma unroll
            for (int r = 0; r < 4; ++r)
                p4[r] = (__bf16)__builtin_amdgcn_exp2f(sf[ns][r] * SCALE_LOG2E);
            *(unsigned long long*)&Ps[wave][l16][ns * 16 + quad * 4] =
                *(unsigned long long*)p4;
        }

        // P fragments (B operands): row q=l16, keys ch*32+quad*8..+7
        bf16x8 ap[2];
        ap[0] = *(const bf16x8*)&Ps[wave][l16][quad * 8];
        ap[1] = *(const bf16x8*)&Ps[wave][l16][32 + quad * 8];

        // l[q] += sum_key P[q][key]
        lsum = __builtin_amdgcn_mfma_f32_16x16x32_bf16(ones, ap[0], lsum, 0, 0, 0);
        lsum = __builtin_amdgcn_mfma_f32_16x16x32_bf16(ones, ap[1], lsum, 0, 0, 0);

        // Ot += V.P^T (consumes vfr — arrived during softmax)
        #pragma unroll
        for (int dsb = 0; dsb < 4; ++dsb) {
            floatx4 cacc = o[dsb];
            #pragma unroll
            for (int ch = 0; ch < 2; ++ch)
                cacc = __builtin_amdgcn_mfma_f32_16x16x32_bf16(
                    vfr[dsb][ch], ap[ch], cacc, 0, 0, 0);
            o[dsb] = cacc;
        }
    }

    // Epilogue: lane owns q=l16, d = dsb*16 + quad*4 + 0..3 -> 4 x 8B stores
    const long rbase = (long)c * (B * S) + (long)b * S + q0 + wave * 16;
    #pragma unroll
    for (int dsb = 0; dsb < 4; ++dsb) {
        __bf16 p4[4];
        #pragma unroll
        for (int r = 0; r < 4; ++r) p4[r] = (__bf16)o[dsb][r];
        *(unsigned long long*)(Opart + (rbase + l16) * 64 + dsb * 16 + quad * 4) =
            *(unsigned long long*)p4;
    }
    if (quad == 0)
        Lpart[rbase + l16] = lsum[0];
}

// ---------------------------------------------------------------------------
// Kernel 3: combine K-split partials: O = (sum_c O_c) / (sum_c l_c),
// summing only the nc(qt) chunks that exist for this row's q-tile.
// ---------------------------------------------------------------------------
__global__ __launch_bounds__(256) void combine_kernel(
    const __bf16* __restrict__ Opart, const float* __restrict__ Lpart,
    float* __restrict__ Og)
{
    const int idx = blockIdx.x * 256 + threadIdx.x;   // over B*S*8
    const int row = idx >> 3, seg = (idx & 7) * 8;
    const int qt = (row & (S - 1)) >> 6;
    const int nc = (qt >> 3) + 1;                     // ceil((qt+1)/8)
    float acc[8] = {0, 0, 0, 0, 0, 0, 0, 0};
    float l = 0.f;
    for (int c = 0; c < nc; ++c) {
        bf16x8 ov = *(const bf16x8*)(Opart + ((long)c * (B * S) + row) * 64 + seg);
        l += Lpart[(long)c * (B * S) + row];
        #pragma unroll
        for (int j = 0; j < 8; ++j) acc[j] += (float)ov[j];
    }
    const float invl = 1.f / l;
    float* dst = Og + (long)row * 64 + seg;
    float4 o0 = {acc[0] * invl, acc[1] * invl, acc[2] * invl, acc[3] * invl};
    float4 o1 = {acc[4] * invl, acc[5] * invl, acc[6] * invl, acc[7] * invl};
    *(float4*)dst = o0;
    *(float4*)(dst + 4) = o1;
}

extern "C" void kernel_launch(void* const* d_in, const int* in_sizes, int n_in,
                              void* d_out, int out_size, void* d_ws, size_t ws_size,
                              hipStream_t stream)
{
    const float* x  = (const float*)d_in[0];
    const float* WQ = (const float*)d_in[1];
    const float* WK = (const float*)d_in[2];
    const float* WV = (const float*)d_in[3];
    float* out = (float*)d_out;

    __bf16* Qb = (__bf16*)d_ws;                       // [B*S, 64]        2 MB
    __bf16* Kb = Qb + (size_t)B * S * D;              //                  2 MB
    __bf16* Vt = Kb + (size_t)B * S * D;              // [B, 64, S]       2 MB
    __bf16* Wt = Vt + (size_t)B * S * D;              // [3, 64, 512]   192 KB
    __bf16* Opart = Wt + (size_t)3 * E * D;           // [8, B*S, 64]    16 MB
    float*  Lpart = (float*)(Opart + (size_t)8 * B * S * D);  // [8,B*S] 512 KB

    prep_wt<<<dim3(24), 256, 0, stream>>>(WQ, WK, WV, Wt);
    qkv_mfma<<<dim3((B * S) / 32), 256, 0, stream>>>(x, Wt, Qb, Kb, Vt);
    attn_kernel<<<dim3(288, B), 256, 0, stream>>>(Qb, Kb, Vt, Opart, Lpart);
    combine_kernel<<<dim3((B * S * 8) / 256), 256, 0, stream>>>(Opart, Lpart, out);
}

// Round 9
// 123.365 us; speedup vs baseline: 1.4362x; 1.3787x over previous
//
#include <hip/hip_runtime.h>
#include <hip/hip_bf16.h>

// B=4, S=4096, E=512, D=64. Causal single-head attention, scale = 1/sqrt(E).
namespace {
constexpr int B = 4, S = 4096, E = 512, D = 64;
constexpr int CHUNK = 8;                      // K-tiles per attention block
// p = exp(scale*s) = exp2(C*s), C = (1/sqrt(512))*log2(e)
constexpr float SCALE_LOG2E = 0.04419417382415922f * 1.4426950408889634f;

typedef __bf16 bf16x8 __attribute__((ext_vector_type(8)));
typedef float floatx4 __attribute__((ext_vector_type(4)));
} // namespace

// ---------------------------------------------------------------------------
// Kernel 0: weight transpose + bf16 cast via LDS tile. Wt[mat][n][k]=W[k][n].
// ---------------------------------------------------------------------------
__global__ __launch_bounds__(256) void prep_wt(
    const float* __restrict__ WQ, const float* __restrict__ WK,
    const float* __restrict__ WV, __bf16* __restrict__ Wt)
{
    __shared__ __bf16 tile[64][72];
    const int t = threadIdx.x;
    const int mat = blockIdx.x >> 3;          // 0..2
    const int k0  = (blockIdx.x & 7) * 64;    // k tile base
    const float* W = (mat == 0) ? WQ : (mat == 1) ? WK : WV;
    #pragma unroll
    for (int i = 0; i < 16; ++i) {
        const int k = (t >> 6) + i * 4;       // lanes vary n -> coalesced read
        tile[t & 63][k] = (__bf16)W[(k0 + k) * 64 + (t & 63)];
    }
    __syncthreads();
    #pragma unroll
    for (int i = 0; i < 2; ++i) {
        const int u = t + 256 * i;            // 512 units: 64 n x 8 k-segs
        const int n = u >> 3, kseg = (u & 7) * 8;
        *(bf16x8*)(Wt + (mat * 64 + n) * 512 + k0 + kseg) =
            *(const bf16x8*)&tile[n][kseg];
    }
}

// ---------------------------------------------------------------------------
// Kernel 1: fused QKV projection as MFMA GEMM [16384 x 512] x [512 x 192].
// B-fragments (Wt) loaded directly from global (L2-resident); x tile staged
// through LDS with register prefetch pipeline. (unchanged from round 6)
// ---------------------------------------------------------------------------
__global__ __launch_bounds__(256) void qkv_mfma(
    const float* __restrict__ x, const __bf16* __restrict__ Wt,
    __bf16* __restrict__ Qb, __bf16* __restrict__ Kb, __bf16* __restrict__ Vt)
{
    __shared__ __bf16 xs[32][72];    // [row][k] staged x tile
    __shared__ __bf16 vsh[64][40];   // V transpose buffer [d][m]

    const int t = threadIdx.x;
    const int wave = t >> 6, lane = t & 63, quad = lane >> 4, l16 = lane & 15;
    const long row0 = (long)blockIdx.x * 32;
    const int xrr = t >> 3, xcc = (t & 7) * 8;   // x staging coords

    const __bf16* wbase = Wt + (wave * 48 + l16) * 512 + quad * 8;

    floatx4 acc[2][3];
    #pragma unroll
    for (int m = 0; m < 2; ++m)
        #pragma unroll
        for (int n = 0; n < 3; ++n) acc[m][n] = (floatx4){0.f, 0.f, 0.f, 0.f};

    float4 xf0, xf1;
    bf16x8 wf[6];
    {
        const float* src = x + (row0 + xrr) * E + xcc;
        xf0 = *(const float4*)src;
        xf1 = *(const float4*)(src + 4);
        #pragma unroll
        for (int ns = 0; ns < 3; ++ns)
            #pragma unroll
            for (int ch = 0; ch < 2; ++ch)
                wf[ns * 2 + ch] = *(const bf16x8*)(wbase + ns * 16 * 512 + ch * 32);
    }

    #pragma unroll
    for (int kc = 0; kc < 8; ++kc) {
        __syncthreads();
        {   // commit prefetched x regs to LDS (fp32 -> bf16)
            bf16x8 v;
            v[0] = (__bf16)xf0.x; v[1] = (__bf16)xf0.y;
            v[2] = (__bf16)xf0.z; v[3] = (__bf16)xf0.w;
            v[4] = (__bf16)xf1.x; v[5] = (__bf16)xf1.y;
            v[6] = (__bf16)xf1.z; v[7] = (__bf16)xf1.w;
            *(bf16x8*)&xs[xrr][xcc] = v;
        }
        __syncthreads();

        bf16x8 wcur[6];
        #pragma unroll
        for (int i = 0; i < 6; ++i) wcur[i] = wf[i];

        if (kc < 7) {
            const float* src = x + (row0 + xrr) * E + (kc + 1) * 64 + xcc;
            xf0 = *(const float4*)src;
            xf1 = *(const float4*)(src + 4);
            #pragma unroll
            for (int ns = 0; ns < 3; ++ns)
                #pragma unroll
                for (int ch = 0; ch < 2; ++ch)
                    wf[ns * 2 + ch] =
                        *(const bf16x8*)(wbase + ns * 16 * 512 + (kc + 1) * 64 + ch * 32);
        }

        bf16x8 aa[2][2];
        #pragma unroll
        for (int m = 0; m < 2; ++m)
            #pragma unroll
            for (int ch = 0; ch < 2; ++ch)
                aa[m][ch] = *(const bf16x8*)&xs[m * 16 + l16][ch * 32 + quad * 8];
        #pragma unroll
        for (int ns = 0; ns < 3; ++ns) {
            #pragma unroll
            for (int ch = 0; ch < 2; ++ch) {
                #pragma unroll
                for (int m = 0; m < 2; ++m)
                    acc[m][ns] = __builtin_amdgcn_mfma_f32_16x16x32_bf16(
                        aa[m][ch], wcur[ns * 2 + ch], acc[m][ns], 0, 0, 0);
            }
        }
    }

    const long bb_ = row0 >> 12;
    const int s0 = (int)(row0 & 4095);
    #pragma unroll
    for (int ns = 0; ns < 3; ++ns) {
        const int g = wave * 3 + ns;
        const int mat = g >> 2;
        const int col = (g & 3) * 16 + l16;
        #pragma unroll
        for (int m = 0; m < 2; ++m) {
            if (mat < 2) {
                __bf16* Out = (mat == 0) ? Qb : Kb;
                #pragma unroll
                for (int r = 0; r < 4; ++r)
                    Out[(row0 + m * 16 + quad * 4 + r) * 64 + col] = (__bf16)acc[m][ns][r];
            } else {
                __bf16 p[4];
                #pragma unroll
                for (int r = 0; r < 4; ++r) p[r] = (__bf16)acc[m][ns][r];
                *(unsigned long long*)&vsh[col][m * 16 + quad * 4] = *(unsigned long long*)p;
            }
        }
    }
    __syncthreads();
    {
        const int d = t >> 2, seg = (t & 3) * 8;
        bf16x8 v = *(const bf16x8*)&vsh[d][seg];
        *(bf16x8*)(Vt + (bb_ * 64 + d) * 4096 + s0 + seg) = v;
    }
}

// ---------------------------------------------------------------------------
// Kernel 1b: repack K and V^T into MFMA-A-fragment storage order.
// For each 64-key tile kt: 8 blocks (sub*2+ch) of 1 KB, byte offset within a
// block = lane*16 + j*2, where the element at (lane=quad*16+l16, j) is
//   K: K[kt*64 + sub*16 + l16][ch*32 + quad*8 + j]      (sub = key subtile)
//   V: V^T[sub*16 + l16][kt*64 + ch*32 + quad*8 + j]    (sub = d subtile)
// This makes every attention fragment load a single fully-coalesced 1 KB
// wave-load (8 sequential cache lines) instead of 16 scattered lines.
// ---------------------------------------------------------------------------
__global__ __launch_bounds__(256) void repack_kv(
    const __bf16* __restrict__ Kb, const __bf16* __restrict__ Vt,
    __bf16* __restrict__ Kfrag, __bf16* __restrict__ Vfrag)
{
    __shared__ __bf16 Kt[64][72];     // [key][d]
    __shared__ __bf16 Vtl[64][72];    // [d][key]
    const int kt = blockIdx.x, b = blockIdx.y;
    const int t = threadIdx.x;
    {
        const int r = t >> 2, seg = (t & 3) * 16;
        const __bf16* ksrc = Kb + ((long)(b * S + kt * 64 + r)) * 64 + seg;
        *(bf16x8*)&Kt[r][seg]     = *(const bf16x8*)ksrc;
        *(bf16x8*)&Kt[r][seg + 8] = *(const bf16x8*)(ksrc + 8);
        const __bf16* vsrc = Vt + ((long)(b * 64 + r)) * 4096 + kt * 64 + seg;
        *(bf16x8*)&Vtl[r][seg]     = *(const bf16x8*)vsrc;
        *(bf16x8*)&Vtl[r][seg + 8] = *(const bf16x8*)(vsrc + 8);
    }
    __syncthreads();
    const long obase = ((long)(b * 64 + kt)) * 8 * 512;
    #pragma unroll
    for (int i = 0; i < 2; ++i) {
        const int p = t + 256 * i;            // 0..511 pieces of 16B
        const int blk = p >> 6, lane = p & 63;
        const int quad = lane >> 4, l16 = lane & 15;
        const int row = (blk >> 1) * 16 + l16;      // key (K) / d (V)
        const int c0  = (blk & 1) * 32 + quad * 8;  // d (K)  / key (V)
        *(bf16x8*)(Kfrag + obase + blk * 512 + lane * 8) = *(const bf16x8*)&Kt[row][c0];
        *(bf16x8*)(Vfrag + obase + blk * 512 + lane * 8) = *(const bf16x8*)&Vtl[row][c0];
    }
}

// ---------------------------------------------------------------------------
// Kernel 2 v5: barrier-free causal flash attention on fragment-ordered K/V.
// Same math/pipeline as v4 (V issued at tile top, K refilled in-place after
// St, operand-swapped MFMAs, no-max softmax, per-wave P LDS round-trip), but
// every fragment load is now one contiguous 1 KB wave-load from Kfrag/Vfrag;
// the 4 waves of a block read the same 16 KB per tile (L1-served).
// ---------------------------------------------------------------------------
__global__ __launch_bounds__(256) void attn_kernel(
    const __bf16* __restrict__ Qg, const __bf16* __restrict__ Kfrag,
    const __bf16* __restrict__ Vfrag, __bf16* __restrict__ Opart,
    float* __restrict__ Lpart)
{
    __shared__ __bf16 Ps[4][16][72];  // per-wave P [q][key]

    // decode (heavy-first) blockIdx.x -> (qt, chunk)
    int g = 287 - blockIdx.x;         // large g = large qt = heavy chunk
    int a = 0;
    while (g >= 4 * (a + 1) * (a + 2)) ++a;      // a = qt>>3
    const int rem = g - 4 * a * (a + 1);
    const int qt  = 8 * a + rem / (a + 1);
    const int c   = rem % (a + 1);

    const int b  = blockIdx.y;
    const int q0 = qt * 64;
    const int t  = threadIdx.x;
    const int wave = t >> 6, lane = t & 63, quad = lane >> 4, l16 = lane & 15;

    const int nkt    = qt + 1;
    const int kstart = c * CHUNK;
    const int kend   = min(kstart + CHUNK, nkt);

    // Q fragments (MFMA B operands for St)
    const __bf16* qrow = Qg + ((long)(b * S + q0 + wave * 16 + l16)) * D;
    bf16x8 aq[2];
    aq[0] = *(const bf16x8*)(qrow + quad * 8);
    aq[1] = *(const bf16x8*)(qrow + 32 + quad * 8);

    bf16x8 ones;
    #pragma unroll
    for (int j = 0; j < 8; ++j) ones[j] = (__bf16)1.0f;

    floatx4 o[4];                     // Ot: [d-subtile][regs over d]
    #pragma unroll
    for (int i = 0; i < 4; ++i) o[i] = (floatx4){0.f, 0.f, 0.f, 0.f};
    floatx4 lsum = (floatx4){0.f, 0.f, 0.f, 0.f};

    const __bf16* Kf_ = Kfrag + (long)b * 64 * 8 * 512 + lane * 8;
    const __bf16* Vf_ = Vfrag + (long)b * 64 * 8 * 512 + lane * 8;

    // ---- prologue: K fragments for the first tile (only exposed latency)
    bf16x8 kf[4][2];
    #pragma unroll
    for (int ns = 0; ns < 4; ++ns)
        #pragma unroll
        for (int ch = 0; ch < 2; ++ch)
            kf[ns][ch] = *(const bf16x8*)(Kf_ + ((long)kstart * 8 + ns * 2 + ch) * 512);

    for (int ktg = kstart; ktg < kend; ++ktg) {
        // V fragments for THIS tile: issue now, consumed after softmax
        bf16x8 vfr[4][2];
        #pragma unroll
        for (int dsb = 0; dsb < 4; ++dsb)
            #pragma unroll
            for (int ch = 0; ch < 2; ++ch)
                vfr[dsb][ch] = *(const bf16x8*)(Vf_ + ((long)ktg * 8 + dsb * 2 + ch) * 512);

        // St = K.Q^T (consumes kf)
        floatx4 sf[4];
        #pragma unroll
        for (int ns = 0; ns < 4; ++ns) {
            floatx4 cacc = (floatx4){0.f, 0.f, 0.f, 0.f};
            #pragma unroll
            for (int ch = 0; ch < 2; ++ch)
                cacc = __builtin_amdgcn_mfma_f32_16x16x32_bf16(
                    kf[ns][ch], aq[ch], cacc, 0, 0, 0);
            sf[ns] = cacc;
        }

        // K fragments for NEXT tile: in-place refill (WAR at issue, no stall)
        if (ktg + 1 < kend) {
            #pragma unroll
            for (int ns = 0; ns < 4; ++ns)
                #pragma unroll
                for (int ch = 0; ch < 2; ++ch)
                    kf[ns][ch] = *(const bf16x8*)(
                        Kf_ + ((long)(ktg + 1) * 8 + ns * 2 + ch) * 512);
        }

        if (ktg == nkt - 1) {   // diagonal tile: causal mask (St indexing)
            const int q = q0 + wave * 16 + l16;
            const int kbase = ktg * 64;
            #pragma unroll
            for (int ns = 0; ns < 4; ++ns)
                #pragma unroll
                for (int r = 0; r < 4; ++r) {
                    const int key = kbase + ns * 16 + quad * 4 + r;
                    if (key > q) sf[ns][r] = -1e30f;
                }
        }

        // p = exp2(s*C); lane packs its 4 keys of row q=l16 -> b64 per ns
        #pragma unroll
        for (int ns = 0; ns < 4; ++ns) {
            __bf16 p4[4];
            #pragma unroll
            for (int r = 0; r < 4; ++r)
                p4[r] = (__bf16)__builtin_amdgcn_exp2f(sf[ns][r] * SCALE_LOG2E);
            *(unsigned long long*)&Ps[wave][l16][ns * 16 + quad * 4] =
                *(unsigned long long*)p4;
        }

        // P fragments (B operands): row q=l16, keys ch*32+quad*8..+7
        bf16x8 ap[2];
        ap[0] = *(const bf16x8*)&Ps[wave][l16][quad * 8];
        ap[1] = *(const bf16x8*)&Ps[wave][l16][32 + quad * 8];

        // l[q] += sum_key P[q][key]
        lsum = __builtin_amdgcn_mfma_f32_16x16x32_bf16(ones, ap[0], lsum, 0, 0, 0);
        lsum = __builtin_amdgcn_mfma_f32_16x16x32_bf16(ones, ap[1], lsum, 0, 0, 0);

        // Ot += V.P^T (consumes vfr — arrived during softmax)
        #pragma unroll
        for (int dsb = 0; dsb < 4; ++dsb) {
            floatx4 cacc = o[dsb];
            #pragma unroll
            for (int ch = 0; ch < 2; ++ch)
                cacc = __builtin_amdgcn_mfma_f32_16x16x32_bf16(
                    vfr[dsb][ch], ap[ch], cacc, 0, 0, 0);
            o[dsb] = cacc;
        }
    }

    // Epilogue: lane owns q=l16, d = dsb*16 + quad*4 + 0..3 -> 4 x 8B stores
    const long rbase = (long)c * (B * S) + (long)b * S + q0 + wave * 16;
    #pragma unroll
    for (int dsb = 0; dsb < 4; ++dsb) {
        __bf16 p4[4];
        #pragma unroll
        for (int r = 0; r < 4; ++r) p4[r] = (__bf16)o[dsb][r];
        *(unsigned long long*)(Opart + (rbase + l16) * 64 + dsb * 16 + quad * 4) =
            *(unsigned long long*)p4;
    }
    if (quad == 0)
        Lpart[rbase + l16] = lsum[0];
}

// ---------------------------------------------------------------------------
// Kernel 3: combine K-split partials: O = (sum_c O_c) / (sum_c l_c),
// summing only the nc(qt) chunks that exist for this row's q-tile.
// ---------------------------------------------------------------------------
__global__ __launch_bounds__(256) void combine_kernel(
    const __bf16* __restrict__ Opart, const float* __restrict__ Lpart,
    float* __restrict__ Og)
{
    const int idx = blockIdx.x * 256 + threadIdx.x;   // over B*S*8
    const int row = idx >> 3, seg = (idx & 7) * 8;
    const int qt = (row & (S - 1)) >> 6;
    const int nc = (qt >> 3) + 1;                     // ceil((qt+1)/8)
    float acc[8] = {0, 0, 0, 0, 0, 0, 0, 0};
    float l = 0.f;
    for (int c = 0; c < nc; ++c) {
        bf16x8 ov = *(const bf16x8*)(Opart + ((long)c * (B * S) + row) * 64 + seg);
        l += Lpart[(long)c * (B * S) + row];
        #pragma unroll
        for (int j = 0; j < 8; ++j) acc[j] += (float)ov[j];
    }
    const float invl = 1.f / l;
    float* dst = Og + (long)row * 64 + seg;
    float4 o0 = {acc[0] * invl, acc[1] * invl, acc[2] * invl, acc[3] * invl};
    float4 o1 = {acc[4] * invl, acc[5] * invl, acc[6] * invl, acc[7] * invl};
    *(float4*)dst = o0;
    *(float4*)(dst + 4) = o1;
}

extern "C" void kernel_launch(void* const* d_in, const int* in_sizes, int n_in,
                              void* d_out, int out_size, void* d_ws, size_t ws_size,
                              hipStream_t stream)
{
    const float* x  = (const float*)d_in[0];
    const float* WQ = (const float*)d_in[1];
    const float* WK = (const float*)d_in[2];
    const float* WV = (const float*)d_in[3];
    float* out = (float*)d_out;

    __bf16* Qb = (__bf16*)d_ws;                       // [B*S, 64]        2 MB
    __bf16* Kb = Qb + (size_t)B * S * D;              //                  2 MB
    __bf16* Vt = Kb + (size_t)B * S * D;              // [B, 64, S]       2 MB
    __bf16* Wt = Vt + (size_t)B * S * D;              // [3, 64, 512]   192 KB
    __bf16* Opart = Wt + (size_t)3 * E * D;           // [8, B*S, 64]    16 MB
    float*  Lpart = (float*)(Opart + (size_t)8 * B * S * D);  // [8,B*S] 512 KB
    __bf16* Kfrag = (__bf16*)(Lpart + (size_t)8 * B * S);     //          2 MB
    __bf16* Vfrag = Kfrag + (size_t)B * S * D;                //          2 MB

    prep_wt<<<dim3(24), 256, 0, stream>>>(WQ, WK, WV, Wt);
    qkv_mfma<<<dim3((B * S) / 32), 256, 0, stream>>>(x, Wt, Qb, Kb, Vt);
    repack_kv<<<dim3(64, B), 256, 0, stream>>>(Kb, Vt, Kfrag, Vfrag);
    attn_kernel<<<dim3(288, B), 256, 0, stream>>>(Qb, Kfrag, Vfrag, Opart, Lpart);
    combine_kernel<<<dim3((B * S * 8) / 256), 256, 0, stream>>>(Opart, Lpart, out);
}

// Round 10
// 119.784 us; speedup vs baseline: 1.4791x; 1.0299x over previous
//
#include <hip/hip_runtime.h>
#include <hip/hip_bf16.h>

// B=4, S=4096, E=512, D=64. Causal single-head attention, scale = 1/sqrt(E).
namespace {
constexpr int B = 4, S = 4096, E = 512, D = 64;
constexpr int CHUNK = 8;                      // K-tiles per attention block
// p = exp(scale*s) = exp2(C*s), C = (1/sqrt(512))*log2(e)
constexpr float SCALE_LOG2E = 0.04419417382415922f * 1.4426950408889634f;

typedef __bf16 bf16x8 __attribute__((ext_vector_type(8)));
typedef float floatx4 __attribute__((ext_vector_type(4)));
} // namespace

// ---------------------------------------------------------------------------
// Kernel 0: weight transpose + bf16 cast via LDS tile. Wt[mat][n][k]=W[k][n].
// ---------------------------------------------------------------------------
__global__ __launch_bounds__(256) void prep_wt(
    const float* __restrict__ WQ, const float* __restrict__ WK,
    const float* __restrict__ WV, __bf16* __restrict__ Wt)
{
    __shared__ __bf16 tile[64][72];
    const int t = threadIdx.x;
    const int mat = blockIdx.x >> 3;          // 0..2
    const int k0  = (blockIdx.x & 7) * 64;    // k tile base
    const float* W = (mat == 0) ? WQ : (mat == 1) ? WK : WV;
    #pragma unroll
    for (int i = 0; i < 16; ++i) {
        const int k = (t >> 6) + i * 4;       // lanes vary n -> coalesced read
        tile[t & 63][k] = (__bf16)W[(k0 + k) * 64 + (t & 63)];
    }
    __syncthreads();
    #pragma unroll
    for (int i = 0; i < 2; ++i) {
        const int u = t + 256 * i;            // 512 units: 64 n x 8 k-segs
        const int n = u >> 3, kseg = (u & 7) * 8;
        *(bf16x8*)(Wt + (mat * 64 + n) * 512 + k0 + kseg) =
            *(const bf16x8*)&tile[n][kseg];
    }
}

// ---------------------------------------------------------------------------
// Kernel 1: fused QKV projection GEMM [16384 x 512] x [512 x 192], now also
// the K/V FRAGMENT PACKER (repack_kv fused away):
//   Q  -> Qb row-major (4 scalar stores, as before)
//   K  -> Kfrag DIRECTLY in MFMA-A-fragment order (same 4 scalar stores,
//         only the index math changed; C-layout reg r = key l16 slot)
//   V  -> vsh LDS transpose, then writeback straight into Vfrag order:
//         per wave the store address is base + lane*16B = coalesced 1 KB.
// Fragment order (per 64-key tile kt, base (b*64+kt)*4096 elems):
//   block = sub*2 + ch (sub = 16-row subtile, ch = 32-col half),
//   elem  = block*512 + (quad*16 + l16)*8 + j
//   K: row = key, col = d.   V: row = d, col = key.
// ---------------------------------------------------------------------------
__global__ __launch_bounds__(256) void qkv_mfma(
    const float* __restrict__ x, const __bf16* __restrict__ Wt,
    __bf16* __restrict__ Qb, __bf16* __restrict__ Kfrag,
    __bf16* __restrict__ Vfrag)
{
    __shared__ __bf16 xs[32][72];    // [row][k] staged x tile
    __shared__ __bf16 vsh[64][48];   // V transpose buffer [d][token], 96B rows

    const int t = threadIdx.x;
    const int wave = t >> 6, lane = t & 63, quad = lane >> 4, l16 = lane & 15;
    const long row0 = (long)blockIdx.x * 32;
    const int xrr = t >> 3, xcc = (t & 7) * 8;   // x staging coords

    const __bf16* wbase = Wt + (wave * 48 + l16) * 512 + quad * 8;

    floatx4 acc[2][3];
    #pragma unroll
    for (int m = 0; m < 2; ++m)
        #pragma unroll
        for (int n = 0; n < 3; ++n) acc[m][n] = (floatx4){0.f, 0.f, 0.f, 0.f};

    float4 xf0, xf1;
    bf16x8 wf[6];
    {
        const float* src = x + (row0 + xrr) * E + xcc;
        xf0 = *(const float4*)src;
        xf1 = *(const float4*)(src + 4);
        #pragma unroll
        for (int ns = 0; ns < 3; ++ns)
            #pragma unroll
            for (int ch = 0; ch < 2; ++ch)
                wf[ns * 2 + ch] = *(const bf16x8*)(wbase + ns * 16 * 512 + ch * 32);
    }

    #pragma unroll
    for (int kc = 0; kc < 8; ++kc) {
        __syncthreads();
        {   // commit prefetched x regs to LDS (fp32 -> bf16)
            bf16x8 v;
            v[0] = (__bf16)xf0.x; v[1] = (__bf16)xf0.y;
            v[2] = (__bf16)xf0.z; v[3] = (__bf16)xf0.w;
            v[4] = (__bf16)xf1.x; v[5] = (__bf16)xf1.y;
            v[6] = (__bf16)xf1.z; v[7] = (__bf16)xf1.w;
            *(bf16x8*)&xs[xrr][xcc] = v;
        }
        __syncthreads();

        bf16x8 wcur[6];
        #pragma unroll
        for (int i = 0; i < 6; ++i) wcur[i] = wf[i];

        if (kc < 7) {
            const float* src = x + (row0 + xrr) * E + (kc + 1) * 64 + xcc;
            xf0 = *(const float4*)src;
            xf1 = *(const float4*)(src + 4);
            #pragma unroll
            for (int ns = 0; ns < 3; ++ns)
                #pragma unroll
                for (int ch = 0; ch < 2; ++ch)
                    wf[ns * 2 + ch] =
                        *(const bf16x8*)(wbase + ns * 16 * 512 + (kc + 1) * 64 + ch * 32);
        }

        bf16x8 aa[2][2];
        #pragma unroll
        for (int m = 0; m < 2; ++m)
            #pragma unroll
            for (int ch = 0; ch < 2; ++ch)
                aa[m][ch] = *(const bf16x8*)&xs[m * 16 + l16][ch * 32 + quad * 8];
        #pragma unroll
        for (int ns = 0; ns < 3; ++ns) {
            #pragma unroll
            for (int ch = 0; ch < 2; ++ch) {
                #pragma unroll
                for (int m = 0; m < 2; ++m)
                    acc[m][ns] = __builtin_amdgcn_mfma_f32_16x16x32_bf16(
                        aa[m][ch], wcur[ns * 2 + ch], acc[m][ns], 0, 0, 0);
            }
        }
    }

    const long bb_ = row0 >> 12;            // batch
    const int s0 = (int)(row0 & 4095);      // token offset within batch
    const int kt = s0 >> 6;                 // 64-key tile index
    const int ch_tok = (s0 >> 5) & 1;       // which 32-token half of the tile
    const long kvobase = ((long)(bb_ * 64 + kt)) * 4096;   // 8 blocks x 512

    #pragma unroll
    for (int ns = 0; ns < 3; ++ns) {
        const int g = wave * 3 + ns;
        const int mat = g >> 2;
        const int col = (g & 3) * 16 + l16;
        #pragma unroll
        for (int m = 0; m < 2; ++m) {
            if (mat == 0) {                 // Q row-major
                #pragma unroll
                for (int r = 0; r < 4; ++r)
                    Qb[(row0 + m * 16 + quad * 4 + r) * 64 + col] = (__bf16)acc[m][ns][r];
            } else if (mat == 1) {          // K -> Kfrag direct
                const int d  = col;
                const int ch = d >> 5, kq = (d & 31) >> 3, j = d & 7;
                const int sub = ch_tok * 2 + m;      // key subtile within kt
                #pragma unroll
                for (int r = 0; r < 4; ++r) {
                    const int kl = quad * 4 + r;     // key l16 slot
                    Kfrag[kvobase + (sub * 2 + ch) * 512 + (kq * 16 + kl) * 8 + j]
                        = (__bf16)acc[m][ns][r];
                }
            } else {                        // V -> vsh [d][token]
                __bf16 p[4];
                #pragma unroll
                for (int r = 0; r < 4; ++r) p[r] = (__bf16)acc[m][ns][r];
                *(unsigned long long*)&vsh[col][m * 16 + quad * 4] =
                    *(unsigned long long*)p;
            }
        }
    }
    __syncthreads();
    {   // Vfrag writeback: thread t -> d = dsb*16+dl, tokens q*8..q*8+7
        const int dsb = t >> 6, q = (t >> 4) & 3, dl = t & 15;
        bf16x8 v = *(const bf16x8*)&vsh[dsb * 16 + dl][q * 8];
        *(bf16x8*)(Vfrag + kvobase + (dsb * 2 + ch_tok) * 512 + (q * 16 + dl) * 8) = v;
    }
}

// ---------------------------------------------------------------------------
// Kernel 2: barrier-free causal flash attention on fragment-ordered K/V.
// (unchanged from round 9 — V issued at tile top, K refilled in-place after
// St, operand-swapped MFMAs, no-max softmax, per-wave P LDS round-trip.)
// ---------------------------------------------------------------------------
__global__ __launch_bounds__(256) void attn_kernel(
    const __bf16* __restrict__ Qg, const __bf16* __restrict__ Kfrag,
    const __bf16* __restrict__ Vfrag, __bf16* __restrict__ Opart,
    float* __restrict__ Lpart)
{
    __shared__ __bf16 Ps[4][16][72];  // per-wave P [q][key]

    // decode (heavy-first) blockIdx.x -> (qt, chunk)
    int g = 287 - blockIdx.x;         // large g = large qt = heavy chunk
    int a = 0;
    while (g >= 4 * (a + 1) * (a + 2)) ++a;      // a = qt>>3
    const int rem = g - 4 * a * (a + 1);
    const int qt  = 8 * a + rem / (a + 1);
    const int c   = rem % (a + 1);

    const int b  = blockIdx.y;
    const int q0 = qt * 64;
    const int t  = threadIdx.x;
    const int wave = t >> 6, lane = t & 63, quad = lane >> 4, l16 = lane & 15;

    const int nkt    = qt + 1;
    const int kstart = c * CHUNK;
    const int kend   = min(kstart + CHUNK, nkt);

    // Q fragments (MFMA B operands for St)
    const __bf16* qrow = Qg + ((long)(b * S + q0 + wave * 16 + l16)) * D;
    bf16x8 aq[2];
    aq[0] = *(const bf16x8*)(qrow + quad * 8);
    aq[1] = *(const bf16x8*)(qrow + 32 + quad * 8);

    bf16x8 ones;
    #pragma unroll
    for (int j = 0; j < 8; ++j) ones[j] = (__bf16)1.0f;

    floatx4 o[4];                     // Ot: [d-subtile][regs over d]
    #pragma unroll
    for (int i = 0; i < 4; ++i) o[i] = (floatx4){0.f, 0.f, 0.f, 0.f};
    floatx4 lsum = (floatx4){0.f, 0.f, 0.f, 0.f};

    const __bf16* Kf_ = Kfrag + (long)b * 64 * 8 * 512 + lane * 8;
    const __bf16* Vf_ = Vfrag + (long)b * 64 * 8 * 512 + lane * 8;

    // ---- prologue: K fragments for the first tile (only exposed latency)
    bf16x8 kf[4][2];
    #pragma unroll
    for (int ns = 0; ns < 4; ++ns)
        #pragma unroll
        for (int ch = 0; ch < 2; ++ch)
            kf[ns][ch] = *(const bf16x8*)(Kf_ + ((long)kstart * 8 + ns * 2 + ch) * 512);

    for (int ktg = kstart; ktg < kend; ++ktg) {
        // V fragments for THIS tile: issue now, consumed after softmax
        bf16x8 vfr[4][2];
        #pragma unroll
        for (int dsb = 0; dsb < 4; ++dsb)
            #pragma unroll
            for (int ch = 0; ch < 2; ++ch)
                vfr[dsb][ch] = *(const bf16x8*)(Vf_ + ((long)ktg * 8 + dsb * 2 + ch) * 512);

        // St = K.Q^T (consumes kf)
        floatx4 sf[4];
        #pragma unroll
        for (int ns = 0; ns < 4; ++ns) {
            floatx4 cacc = (floatx4){0.f, 0.f, 0.f, 0.f};
            #pragma unroll
            for (int ch = 0; ch < 2; ++ch)
                cacc = __builtin_amdgcn_mfma_f32_16x16x32_bf16(
                    kf[ns][ch], aq[ch], cacc, 0, 0, 0);
            sf[ns] = cacc;
        }

        // K fragments for NEXT tile: in-place refill (WAR at issue, no stall)
        if (ktg + 1 < kend) {
            #pragma unroll
            for (int ns = 0; ns < 4; ++ns)
                #pragma unroll
                for (int ch = 0; ch < 2; ++ch)
                    kf[ns][ch] = *(const bf16x8*)(
                        Kf_ + ((long)(ktg + 1) * 8 + ns * 2 + ch) * 512);
        }

        if (ktg == nkt - 1) {   // diagonal tile: causal mask (St indexing)
            const int q = q0 + wave * 16 + l16;
            const int kbase = ktg * 64;
            #pragma unroll
            for (int ns = 0; ns < 4; ++ns)
                #pragma unroll
                for (int r = 0; r < 4; ++r) {
                    const int key = kbase + ns * 16 + quad * 4 + r;
                    if (key > q) sf[ns][r] = -1e30f;
                }
        }

        // p = exp2(s*C); lane packs its 4 keys of row q=l16 -> b64 per ns
        #pragma unroll
        for (int ns = 0; ns < 4; ++ns) {
            __bf16 p4[4];
            #pragma unroll
            for (int r = 0; r < 4; ++r)
                p4[r] = (__bf16)__builtin_amdgcn_exp2f(sf[ns][r] * SCALE_LOG2E);
            *(unsigned long long*)&Ps[wave][l16][ns * 16 + quad * 4] =
                *(unsigned long long*)p4;
        }

        // P fragments (B operands): row q=l16, keys ch*32+quad*8..+7
        bf16x8 ap[2];
        ap[0] = *(const bf16x8*)&Ps[wave][l16][quad * 8];
        ap[1] = *(const bf16x8*)&Ps[wave][l16][32 + quad * 8];

        // l[q] += sum_key P[q][key]
        lsum = __builtin_amdgcn_mfma_f32_16x16x32_bf16(ones, ap[0], lsum, 0, 0, 0);
        lsum = __builtin_amdgcn_mfma_f32_16x16x32_bf16(ones, ap[1], lsum, 0, 0, 0);

        // Ot += V.P^T (consumes vfr — arrived during softmax)
        #pragma unroll
        for (int dsb = 0; dsb < 4; ++dsb) {
            floatx4 cacc = o[dsb];
            #pragma unroll
            for (int ch = 0; ch < 2; ++ch)
                cacc = __builtin_amdgcn_mfma_f32_16x16x32_bf16(
                    vfr[dsb][ch], ap[ch], cacc, 0, 0, 0);
            o[dsb] = cacc;
        }
    }

    // Epilogue: lane owns q=l16, d = dsb*16 + quad*4 + 0..3 -> 4 x 8B stores
    const long rbase = (long)c * (B * S) + (long)b * S + q0 + wave * 16;
    #pragma unroll
    for (int dsb = 0; dsb < 4; ++dsb) {
        __bf16 p4[4];
        #pragma unroll
        for (int r = 0; r < 4; ++r) p4[r] = (__bf16)o[dsb][r];
        *(unsigned long long*)(Opart + (rbase + l16) * 64 + dsb * 16 + quad * 4) =
            *(unsigned long long*)p4;
    }
    if (quad == 0)
        Lpart[rbase + l16] = lsum[0];
}

// ---------------------------------------------------------------------------
// Kernel 3: combine K-split partials: O = (sum_c O_c) / (sum_c l_c),
// summing only the nc(qt) chunks that exist for this row's q-tile.
// ---------------------------------------------------------------------------
__global__ __launch_bounds__(256) void combine_kernel(
    const __bf16* __restrict__ Opart, const float* __restrict__ Lpart,
    float* __restrict__ Og)
{
    const int idx = blockIdx.x * 256 + threadIdx.x;   // over B*S*8
    const int row = idx >> 3, seg = (idx & 7) * 8;
    const int qt = (row & (S - 1)) >> 6;
    const int nc = (qt >> 3) + 1;                     // ceil((qt+1)/8)
    float acc[8] = {0, 0, 0, 0, 0, 0, 0, 0};
    float l = 0.f;
    for (int c = 0; c < nc; ++c) {
        bf16x8 ov = *(const bf16x8*)(Opart + ((long)c * (B * S) + row) * 64 + seg);
        l += Lpart[(long)c * (B * S) + row];
        #pragma unroll
        for (int j = 0; j < 8; ++j) acc[j] += (float)ov[j];
    }
    const float invl = 1.f / l;
    float* dst = Og + (long)row * 64 + seg;
    float4 o0 = {acc[0] * invl, acc[1] * invl, acc[2] * invl, acc[3] * invl};
    float4 o1 = {acc[4] * invl, acc[5] * invl, acc[6] * invl, acc[7] * invl};
    *(float4*)dst = o0;
    *(float4*)(dst + 4) = o1;
}

extern "C" void kernel_launch(void* const* d_in, const int* in_sizes, int n_in,
                              void* d_out, int out_size, void* d_ws, size_t ws_size,
                              hipStream_t stream)
{
    const float* x  = (const float*)d_in[0];
    const float* WQ = (const float*)d_in[1];
    const float* WK = (const float*)d_in[2];
    const float* WV = (const float*)d_in[3];
    float* out = (float*)d_out;

    __bf16* Qb = (__bf16*)d_ws;                       // [B*S, 64]        2 MB
    __bf16* Kfrag = Qb + (size_t)B * S * D;           // fragment order   2 MB
    __bf16* Vfrag = Kfrag + (size_t)B * S * D;        // fragment order   2 MB
    __bf16* Wt = Vfrag + (size_t)B * S * D;           // [3, 64, 512]   192 KB
    __bf16* Opart = Wt + (size_t)3 * E * D;           // [8, B*S, 64]    16 MB
    float*  Lpart = (float*)(Opart + (size_t)8 * B * S * D);  // [8,B*S] 512 KB

    prep_wt<<<dim3(24), 256, 0, stream>>>(WQ, WK, WV, Wt);
    qkv_mfma<<<dim3((B * S) / 32), 256, 0, stream>>>(x, Wt, Qb, Kfrag, Vfrag);
    attn_kernel<<<dim3(288, B), 256, 0, stream>>>(Qb, Kfrag, Vfrag, Opart, Lpart);
    combine_kernel<<<dim3((B * S * 8) / 256), 256, 0, stream>>>(Opart, Lpart, out);
}

// Round 11
// 117.163 us; speedup vs baseline: 1.5122x; 1.0224x over previous
//
#include <hip/hip_runtime.h>
#include <hip/hip_bf16.h>

// B=4, S=4096, E=512, D=64. Causal single-head attention, scale = 1/sqrt(E).
namespace {
constexpr int B = 4, S = 4096, E = 512, D = 64;
constexpr int CHUNK = 8;                      // K-tiles per attention block
// p = exp(scale*s) = exp2(C*s), C = (1/sqrt(512))*log2(e)
constexpr float SCALE_LOG2E = 0.04419417382415922f * 1.4426950408889634f;

typedef __bf16 bf16x8 __attribute__((ext_vector_type(8)));
typedef float floatx4 __attribute__((ext_vector_type(4)));
} // namespace

// ---------------------------------------------------------------------------
// Kernel 0: weight transpose + bf16 cast via LDS tile. Wt[mat][n][k]=W[k][n].
// ---------------------------------------------------------------------------
__global__ __launch_bounds__(256) void prep_wt(
    const float* __restrict__ WQ, const float* __restrict__ WK,
    const float* __restrict__ WV, __bf16* __restrict__ Wt)
{
    __shared__ __bf16 tile[64][72];
    const int t = threadIdx.x;
    const int mat = blockIdx.x >> 3;          // 0..2
    const int k0  = (blockIdx.x & 7) * 64;    // k tile base
    const float* W = (mat == 0) ? WQ : (mat == 1) ? WK : WV;
    #pragma unroll
    for (int i = 0; i < 16; ++i) {
        const int k = (t >> 6) + i * 4;       // lanes vary n -> coalesced read
        tile[t & 63][k] = (__bf16)W[(k0 + k) * 64 + (t & 63)];
    }
    __syncthreads();
    #pragma unroll
    for (int i = 0; i < 2; ++i) {
        const int u = t + 256 * i;            // 512 units: 64 n x 8 k-segs
        const int n = u >> 3, kseg = (u & 7) * 8;
        *(bf16x8*)(Wt + (mat * 64 + n) * 512 + k0 + kseg) =
            *(const bf16x8*)&tile[n][kseg];
    }
}

// ---------------------------------------------------------------------------
// Kernel 1: fused QKV projection GEMM + K/V fragment packer (round 10).
// Q -> Qb row-major; K -> Kfrag directly in MFMA-A-fragment order;
// V -> vsh LDS transpose -> Vfrag (coalesced 1 KB wave stores).
// ---------------------------------------------------------------------------
__global__ __launch_bounds__(256) void qkv_mfma(
    const float* __restrict__ x, const __bf16* __restrict__ Wt,
    __bf16* __restrict__ Qb, __bf16* __restrict__ Kfrag,
    __bf16* __restrict__ Vfrag)
{
    __shared__ __bf16 xs[32][72];    // [row][k] staged x tile
    __shared__ __bf16 vsh[64][48];   // V transpose buffer [d][token]

    const int t = threadIdx.x;
    const int wave = t >> 6, lane = t & 63, quad = lane >> 4, l16 = lane & 15;
    const long row0 = (long)blockIdx.x * 32;
    const int xrr = t >> 3, xcc = (t & 7) * 8;   // x staging coords

    const __bf16* wbase = Wt + (wave * 48 + l16) * 512 + quad * 8;

    floatx4 acc[2][3];
    #pragma unroll
    for (int m = 0; m < 2; ++m)
        #pragma unroll
        for (int n = 0; n < 3; ++n) acc[m][n] = (floatx4){0.f, 0.f, 0.f, 0.f};

    float4 xf0, xf1;
    bf16x8 wf[6];
    {
        const float* src = x + (row0 + xrr) * E + xcc;
        xf0 = *(const float4*)src;
        xf1 = *(const float4*)(src + 4);
        #pragma unroll
        for (int ns = 0; ns < 3; ++ns)
            #pragma unroll
            for (int ch = 0; ch < 2; ++ch)
                wf[ns * 2 + ch] = *(const bf16x8*)(wbase + ns * 16 * 512 + ch * 32);
    }

    #pragma unroll
    for (int kc = 0; kc < 8; ++kc) {
        __syncthreads();
        {   // commit prefetched x regs to LDS (fp32 -> bf16)
            bf16x8 v;
            v[0] = (__bf16)xf0.x; v[1] = (__bf16)xf0.y;
            v[2] = (__bf16)xf0.z; v[3] = (__bf16)xf0.w;
            v[4] = (__bf16)xf1.x; v[5] = (__bf16)xf1.y;
            v[6] = (__bf16)xf1.z; v[7] = (__bf16)xf1.w;
            *(bf16x8*)&xs[xrr][xcc] = v;
        }
        __syncthreads();

        bf16x8 wcur[6];
        #pragma unroll
        for (int i = 0; i < 6; ++i) wcur[i] = wf[i];

        if (kc < 7) {
            const float* src = x + (row0 + xrr) * E + (kc + 1) * 64 + xcc;
            xf0 = *(const float4*)src;
            xf1 = *(const float4*)(src + 4);
            #pragma unroll
            for (int ns = 0; ns < 3; ++ns)
                #pragma unroll
                for (int ch = 0; ch < 2; ++ch)
                    wf[ns * 2 + ch] =
                        *(const bf16x8*)(wbase + ns * 16 * 512 + (kc + 1) * 64 + ch * 32);
        }

        bf16x8 aa[2][2];
        #pragma unroll
        for (int m = 0; m < 2; ++m)
            #pragma unroll
            for (int ch = 0; ch < 2; ++ch)
                aa[m][ch] = *(const bf16x8*)&xs[m * 16 + l16][ch * 32 + quad * 8];
        #pragma unroll
        for (int ns = 0; ns < 3; ++ns) {
            #pragma unroll
            for (int ch = 0; ch < 2; ++ch) {
                #pragma unroll
                for (int m = 0; m < 2; ++m)
                    acc[m][ns] = __builtin_amdgcn_mfma_f32_16x16x32_bf16(
                        aa[m][ch], wcur[ns * 2 + ch], acc[m][ns], 0, 0, 0);
            }
        }
    }

    const long bb_ = row0 >> 12;            // batch
    const int s0 = (int)(row0 & 4095);      // token offset within batch
    const int kt = s0 >> 6;                 // 64-key tile index
    const int ch_tok = (s0 >> 5) & 1;       // which 32-token half of the tile
    const long kvobase = ((long)(bb_ * 64 + kt)) * 4096;   // 8 blocks x 512

    #pragma unroll
    for (int ns = 0; ns < 3; ++ns) {
        const int g = wave * 3 + ns;
        const int mat = g >> 2;
        const int col = (g & 3) * 16 + l16;
        #pragma unroll
        for (int m = 0; m < 2; ++m) {
            if (mat == 0) {                 // Q row-major
                #pragma unroll
                for (int r = 0; r < 4; ++r)
                    Qb[(row0 + m * 16 + quad * 4 + r) * 64 + col] = (__bf16)acc[m][ns][r];
            } else if (mat == 1) {          // K -> Kfrag direct
                const int d  = col;
                const int ch = d >> 5, kq = (d & 31) >> 3, j = d & 7;
                const int sub = ch_tok * 2 + m;      // key subtile within kt
                #pragma unroll
                for (int r = 0; r < 4; ++r) {
                    const int kl = quad * 4 + r;     // key l16 slot
                    Kfrag[kvobase + (sub * 2 + ch) * 512 + (kq * 16 + kl) * 8 + j]
                        = (__bf16)acc[m][ns][r];
                }
            } else {                        // V -> vsh [d][token]
                __bf16 p[4];
                #pragma unroll
                for (int r = 0; r < 4; ++r) p[r] = (__bf16)acc[m][ns][r];
                *(unsigned long long*)&vsh[col][m * 16 + quad * 4] =
                    *(unsigned long long*)p;
            }
        }
    }
    __syncthreads();
    {   // Vfrag writeback: thread t -> d = dsb*16+dl, tokens q*8..q*8+7
        const int dsb = t >> 6, q = (t >> 4) & 3, dl = t & 15;
        bf16x8 v = *(const bf16x8*)&vsh[dsb * 16 + dl][q * 8];
        *(bf16x8*)(Vfrag + kvobase + (dsb * 2 + ch_tok) * 512 + (q * 16 + dl) * 8) = v;
    }
}

// ---------------------------------------------------------------------------
// Kernel 2 v6: barrier-free causal flash attention, 32 QUERIES PER WAVE
// (BQ=128 per block). Same pipeline as v5 (V at tile top, K refilled
// in-place after St, operand-swapped MFMAs, no-max softmax), but each wave
// carries TWO Q fragments -> the 16 KB/tile K+V load feeds 36 MFMAs instead
// of 18, halving total K/V VMEM traffic (532 -> 266 MB). Waves also clip
// their K-loop at their own causal limit (no barriers -> free divergence),
// eliminating fully-masked tail tiles.
// Decomposition: 32 q-tiles of 128 q; nc(qt2) = (qt2>>2)+1 chunks of <=8
// K-tiles; group a = qt2>>2 starts at block 2a(a+1); 144 blocks/batch.
// ---------------------------------------------------------------------------
__global__ __launch_bounds__(256) void attn_kernel(
    const __bf16* __restrict__ Qg, const __bf16* __restrict__ Kfrag,
    const __bf16* __restrict__ Vfrag, __bf16* __restrict__ Opart,
    float* __restrict__ Lpart)
{
    __shared__ __bf16 Ps[4][2][16][72];  // per-wave, per-q-fragment P [q][key]

    // decode (heavy-first) blockIdx.x -> (qt2, chunk)
    int g = 143 - blockIdx.x;
    int a = 0;
    while (g >= 2 * (a + 1) * (a + 2)) ++a;      // a = qt2>>2
    const int rem = g - 2 * a * (a + 1);
    const int qt2 = 4 * a + rem / (a + 1);
    const int c   = rem % (a + 1);

    const int b  = blockIdx.y;
    const int q0 = qt2 * 128;
    const int t  = threadIdx.x;
    const int wave = t >> 6, lane = t & 63, quad = lane >> 4, l16 = lane & 15;

    // per-wave causal K-tile count: waves 0,1 cover q0..q0+63 -> 2qt2+1 tiles
    const int nkt_w  = 2 * qt2 + 1 + (wave >> 1);
    const int kstart = c * CHUNK;
    const int kend   = min(kstart + CHUNK, nkt_w);

    // Q fragments (MFMA B operands), qm = 0,1 -> q rows q0+wave*32+qm*16+l16
    bf16x8 aq[2][2];
    #pragma unroll
    for (int qm = 0; qm < 2; ++qm) {
        const __bf16* qrow =
            Qg + ((long)(b * S + q0 + wave * 32 + qm * 16 + l16)) * D;
        aq[qm][0] = *(const bf16x8*)(qrow + quad * 8);
        aq[qm][1] = *(const bf16x8*)(qrow + 32 + quad * 8);
    }

    bf16x8 ones;
    #pragma unroll
    for (int j = 0; j < 8; ++j) ones[j] = (__bf16)1.0f;

    floatx4 o[2][4];                 // [qm][d-subtile]
    #pragma unroll
    for (int qm = 0; qm < 2; ++qm)
        #pragma unroll
        for (int i = 0; i < 4; ++i) o[qm][i] = (floatx4){0.f, 0.f, 0.f, 0.f};
    floatx4 lsum[2] = {(floatx4){0.f, 0.f, 0.f, 0.f}, (floatx4){0.f, 0.f, 0.f, 0.f}};

    const __bf16* Kf_ = Kfrag + (long)b * 64 * 8 * 512 + lane * 8;
    const __bf16* Vf_ = Vfrag + (long)b * 64 * 8 * 512 + lane * 8;

    // ---- prologue: K fragments for the first tile (only exposed latency)
    bf16x8 kf[4][2];
    #pragma unroll
    for (int ns = 0; ns < 4; ++ns)
        #pragma unroll
        for (int ch = 0; ch < 2; ++ch)
            kf[ns][ch] = *(const bf16x8*)(Kf_ + ((long)kstart * 8 + ns * 2 + ch) * 512);

    for (int ktg = kstart; ktg < kend; ++ktg) {
        const int kbase = ktg * 64;

        // V fragments for THIS tile: issue now, consumed after softmax
        bf16x8 vfr[4][2];
        #pragma unroll
        for (int dsb = 0; dsb < 4; ++dsb)
            #pragma unroll
            for (int ch = 0; ch < 2; ++ch)
                vfr[dsb][ch] = *(const bf16x8*)(Vf_ + ((long)ktg * 8 + dsb * 2 + ch) * 512);

        // St = K.Q^T for both q-fragments (consumes kf)
        floatx4 sf[2][4];
        #pragma unroll
        for (int qm = 0; qm < 2; ++qm)
            #pragma unroll
            for (int ns = 0; ns < 4; ++ns) {
                floatx4 cacc = (floatx4){0.f, 0.f, 0.f, 0.f};
                #pragma unroll
                for (int ch = 0; ch < 2; ++ch)
                    cacc = __builtin_amdgcn_mfma_f32_16x16x32_bf16(
                        kf[ns][ch], aq[qm][ch], cacc, 0, 0, 0);
                sf[qm][ns] = cacc;
            }

        // K fragments for NEXT tile: in-place refill (WAR at issue)
        if (ktg + 1 < kend) {
            #pragma unroll
            for (int ns = 0; ns < 4; ++ns)
                #pragma unroll
                for (int ch = 0; ch < 2; ++ch)
                    kf[ns][ch] = *(const bf16x8*)(
                        Kf_ + ((long)(ktg + 1) * 8 + ns * 2 + ch) * 512);
        }

        // causal mask (only near-diagonal tiles per fragment)
        #pragma unroll
        for (int qm = 0; qm < 2; ++qm) {
            const int qfb = q0 + wave * 32 + qm * 16;   // fragment q base
            if (kbase + 63 > qfb) {
                const int q = qfb + l16;
                #pragma unroll
                for (int ns = 0; ns < 4; ++ns)
                    #pragma unroll
                    for (int r = 0; r < 4; ++r) {
                        const int key = kbase + ns * 16 + quad * 4 + r;
                        if (key > q) sf[qm][ns][r] = -1e30f;
                    }
            }
        }

        // p = exp2(s*C); lane packs its 4 keys of row q=l16 -> b64 per ns
        #pragma unroll
        for (int qm = 0; qm < 2; ++qm)
            #pragma unroll
            for (int ns = 0; ns < 4; ++ns) {
                __bf16 p4[4];
                #pragma unroll
                for (int r = 0; r < 4; ++r)
                    p4[r] = (__bf16)__builtin_amdgcn_exp2f(sf[qm][ns][r] * SCALE_LOG2E);
                *(unsigned long long*)&Ps[wave][qm][l16][ns * 16 + quad * 4] =
                    *(unsigned long long*)p4;
            }

        // PV per q-fragment
        #pragma unroll
        for (int qm = 0; qm < 2; ++qm) {
            bf16x8 ap[2];
            ap[0] = *(const bf16x8*)&Ps[wave][qm][l16][quad * 8];
            ap[1] = *(const bf16x8*)&Ps[wave][qm][l16][32 + quad * 8];

            lsum[qm] = __builtin_amdgcn_mfma_f32_16x16x32_bf16(ones, ap[0], lsum[qm], 0, 0, 0);
            lsum[qm] = __builtin_amdgcn_mfma_f32_16x16x32_bf16(ones, ap[1], lsum[qm], 0, 0, 0);

            #pragma unroll
            for (int dsb = 0; dsb < 4; ++dsb) {
                floatx4 cacc = o[qm][dsb];
                #pragma unroll
                for (int ch = 0; ch < 2; ++ch)
                    cacc = __builtin_amdgcn_mfma_f32_16x16x32_bf16(
                        vfr[dsb][ch], ap[ch], cacc, 0, 0, 0);
                o[qm][dsb] = cacc;
            }
        }
    }

    // Epilogue: per qm, lane owns q=l16, d = dsb*16+quad*4+0..3
    const long rbase = (long)c * (B * S) + (long)b * S + q0 + wave * 32;
    #pragma unroll
    for (int qm = 0; qm < 2; ++qm) {
        #pragma unroll
        for (int dsb = 0; dsb < 4; ++dsb) {
            __bf16 p4[4];
            #pragma unroll
            for (int r = 0; r < 4; ++r) p4[r] = (__bf16)o[qm][dsb][r];
            *(unsigned long long*)(Opart + (rbase + qm * 16 + l16) * 64 + dsb * 16 + quad * 4) =
                *(unsigned long long*)p4;
        }
        if (quad == 0)
            Lpart[rbase + qm * 16 + l16] = lsum[qm][0];
    }
}

// ---------------------------------------------------------------------------
// Kernel 3: combine K-split partials: O = (sum_c O_c) / (sum_c l_c),
// summing only the nc(qt2) = (qt2>>2)+1 chunks that exist for this row.
// ---------------------------------------------------------------------------
__global__ __launch_bounds__(256) void combine_kernel(
    const __bf16* __restrict__ Opart, const float* __restrict__ Lpart,
    float* __restrict__ Og)
{
    const int idx = blockIdx.x * 256 + threadIdx.x;   // over B*S*8
    const int row = idx >> 3, seg = (idx & 7) * 8;
    const int qt2 = (row & (S - 1)) >> 7;
    const int nc = (qt2 >> 2) + 1;
    float acc[8] = {0, 0, 0, 0, 0, 0, 0, 0};
    float l = 0.f;
    for (int c = 0; c < nc; ++c) {
        bf16x8 ov = *(const bf16x8*)(Opart + ((long)c * (B * S) + row) * 64 + seg);
        l += Lpart[(long)c * (B * S) + row];
        #pragma unroll
        for (int j = 0; j < 8; ++j) acc[j] += (float)ov[j];
    }
    const float invl = 1.f / l;
    float* dst = Og + (long)row * 64 + seg;
    float4 o0 = {acc[0] * invl, acc[1] * invl, acc[2] * invl, acc[3] * invl};
    float4 o1 = {acc[4] * invl, acc[5] * invl, acc[6] * invl, acc[7] * invl};
    *(float4*)dst = o0;
    *(float4*)(dst + 4) = o1;
}

extern "C" void kernel_launch(void* const* d_in, const int* in_sizes, int n_in,
                              void* d_out, int out_size, void* d_ws, size_t ws_size,
                              hipStream_t stream)
{
    const float* x  = (const float*)d_in[0];
    const float* WQ = (const float*)d_in[1];
    const float* WK = (const float*)d_in[2];
    const float* WV = (const float*)d_in[3];
    float* out = (float*)d_out;

    __bf16* Qb = (__bf16*)d_ws;                       // [B*S, 64]        2 MB
    __bf16* Kfrag = Qb + (size_t)B * S * D;           // fragment order   2 MB
    __bf16* Vfrag = Kfrag + (size_t)B * S * D;        // fragment order   2 MB
    __bf16* Wt = Vfrag + (size_t)B * S * D;           // [3, 64, 512]   192 KB
    __bf16* Opart = Wt + (size_t)3 * E * D;           // [8, B*S, 64]    16 MB
    float*  Lpart = (float*)(Opart + (size_t)8 * B * S * D);  // [8,B*S] 512 KB

    prep_wt<<<dim3(24), 256, 0, stream>>>(WQ, WK, WV, Wt);
    qkv_mfma<<<dim3((B * S) / 32), 256, 0, stream>>>(x, Wt, Qb, Kfrag, Vfrag);
    attn_kernel<<<dim3(144, B), 256, 0, stream>>>(Qb, Kfrag, Vfrag, Opart, Lpart);
    combine_kernel<<<dim3((B * S * 8) / 256), 256, 0, stream>>>(Opart, Lpart, out);
}